// Round 11
// baseline (156.162 us; speedup 1.0000x reference)
//
#include <hip/hip_runtime.h>

#define BSZ  8192
#define DDIM 256
#define BM 128
#define BN 128
#define NT   64                  // tiles per dimension
#define NTRI (NT * (NT + 1) / 2) // 2080 upper-triangle tiles

typedef float f32x4 __attribute__((ext_vector_type(4)));
typedef short bf16x8 __attribute__((ext_vector_type(8)));

__device__ __forceinline__ unsigned short f32_to_bf16(float f) {
    unsigned int u = __float_as_uint(f);
    u += 0x7fffu + ((u >> 16) & 1u);   // RNE
    return (unsigned short)(u >> 16);
}

__device__ __forceinline__ float fast_exp2(float x) {
    float r;
    asm volatile("v_exp_f32 %0, %1" : "=v"(r) : "v"(x));
    return r;
}

// epilogue constants
#define K_E1   20.60992915555662f    // (1/T)*log2(e)
#define K_E2  -20.60992915555662f
#define K_INVT 14.285714285714286f   // 1/T
#define K_N1   1.4285714285714286f   // 1/(1-0.3)
#define K_N2   0.5714285714285714f   // 0.4/0.7

// ---------------- triangular tile decode (supertile-swizzled) ----------------
__device__ __forceinline__ void decode_tile(int t, int& It, int& Jt) {
    const int off1 = 136, off2 = 392, off3 = 648, off4 = 904, off5 = 1040,
              off6 = 1296, off7 = 1552, off8 = 1688, off9 = 1944;
    int b = (t >= off1) + (t >= off2) + (t >= off3) + (t >= off4) + (t >= off5)
          + (t >= off6) + (t >= off7) + (t >= off8) + (t >= off9);
    int si, sj, r0;
    switch (b) {
        case 0: si = 0; sj = 0; r0 = 0;    break;
        case 1: si = 0; sj = 1; r0 = off1; break;
        case 2: si = 0; sj = 2; r0 = off2; break;
        case 3: si = 0; sj = 3; r0 = off3; break;
        case 4: si = 1; sj = 1; r0 = off4; break;
        case 5: si = 1; sj = 2; r0 = off5; break;
        case 6: si = 1; sj = 3; r0 = off6; break;
        case 7: si = 2; sj = 2; r0 = off7; break;
        case 8: si = 2; sj = 3; r0 = off8; break;
        default: si = 3; sj = 3; r0 = off9; break;
    }
    const int rr = t - r0;
    int il, jl;
    if (si == sj) {
        il = 0;
        #pragma unroll
        for (int q = 1; q < 16; q++) if (rr >= (16 * q - (q * (q - 1)) / 2)) il = q;
        jl = il + (rr - (16 * il - (il * (il - 1)) / 2));
    } else {
        il = rr >> 4;
        jl = rr & 15;
    }
    It = si * 16 + il;
    Jt = sj * 16 + jl;
}

// ---------------- counting sort by label (1 block) ----------------
__global__ __launch_bounds__(256) void sort_kernel(const int* __restrict__ labels,
                                                   int* __restrict__ s2o,
                                                   int* __restrict__ sortedLab,
                                                   unsigned int* __restrict__ counter) {
    __shared__ int hist[1024];
    __shared__ int waveSum[4];
    const int t = threadIdx.x;
    hist[t] = 0; hist[t + 256] = 0; hist[t + 512] = 0; hist[t + 768] = 0;
    __syncthreads();
    for (int i = t; i < BSZ; i += 256) atomicAdd(&hist[labels[i]], 1);
    __syncthreads();
    const int h0 = hist[t * 4], h1 = hist[t * 4 + 1], h2 = hist[t * 4 + 2], h3 = hist[t * 4 + 3];
    const int s = h0 + h1 + h2 + h3;
    const int lane = t & 63, w = t >> 6;
    int sc = s;
    #pragma unroll
    for (int off = 1; off < 64; off <<= 1) {
        const int v = __shfl_up(sc, off, 64);
        if (lane >= off) sc += v;
    }
    if (lane == 63) waveSum[w] = sc;
    __syncthreads();
    int wbase = 0;
    #pragma unroll
    for (int q = 0; q < 4; q++) if (q < w) wbase += waveSum[q];
    const int excl = wbase + sc - s;
    hist[t * 4]     = excl;
    hist[t * 4 + 1] = excl + h0;
    hist[t * 4 + 2] = excl + h0 + h1;
    hist[t * 4 + 3] = excl + h0 + h1 + h2;
    __syncthreads();
    for (int i = t; i < BSZ; i += 256) {
        const int c = labels[i];
        const int p = atomicAdd(&hist[c], 1);
        s2o[p] = i;
        sortedLab[p] = c;
    }
    if (t == 0) *counter = 0u;
}

// ---------------- L2-normalize gathered rows; MFMA-native output; zero posAcc ----------------
// anchorT tile T = C*512 + R (R = sorted row/16), 1 KB each;
// lane l16 = (row%16)+16*((k%32)/8) holds 8 shorts.
__global__ __launch_bounds__(256) void norm_kernel(const float* __restrict__ feat,
                                                   const int* __restrict__ s2o,
                                                   unsigned short* __restrict__ anchorT,
                                                   float* __restrict__ posAcc) {
    __shared__ __align__(16) unsigned short img[8 * 512];    // 8 KB: 8 x 1KB tiles
    const int tid  = threadIdx.x;
    const int wid  = tid >> 6;
    const int lane = tid & 63;
    const int R    = blockIdx.x;          // 16-row tile (sorted space)
    const int R0   = R * 16;

    if (tid < 64) posAcc[blockIdx.x * 64 + tid] = 0.0f;       // 512*64 = 32768 = BSZ*4

    #pragma unroll
    for (int it = 0; it < 4; it++) {
        const int row  = R0 + it * 4 + wid;
        const int orig = s2o[row];
        const float4 v = ((const float4*)(feat + (size_t)orig * DDIM))[lane];
        float ss = v.x * v.x + v.y * v.y + v.z * v.z + v.w * v.w;
        #pragma unroll
        for (int off = 32; off > 0; off >>= 1) ss += __shfl_xor(ss, off, 64);
        const float inv = rsqrtf(ss);
        ushort4 o;
        o.x = f32_to_bf16(v.x * inv);
        o.y = f32_to_bf16(v.y * inv);
        o.z = f32_to_bf16(v.z * inv);
        o.w = f32_to_bf16(v.w * inv);
        const int C    = lane >> 3;                           // k/32 (k = lane*4)
        const int l16  = (row & 15) + (((lane >> 1) & 3) << 4);
        *(ushort4*)(&img[C * 512 + l16 * 8 + (lane & 1) * 4]) = o;
    }
    __syncthreads();
    #pragma unroll
    for (int p = 0; p < 2; p++) {
        const int c = p * 4 + wid;                            // chunk 0..7 (= C)
        *(bf16x8*)(anchorT + ((size_t)(c * 512 + R)) * 512 + lane * 8) =
            *(const bf16x8*)(&img[c * 512 + lane * 8]);
    }
}

// ---------------- async global -> LDS, 16B/lane ----------------
__device__ __forceinline__ void gload_lds16(const unsigned short* g, unsigned short* l) {
    __builtin_amdgcn_global_load_lds(
        (const __attribute__((address_space(1))) void*)g,
        (__attribute__((address_space(3))) void*)l, 16, 0, 0);
}

// ---------------- fused sim-tile + loss partials (upper triangle, sorted space) ----------------
// 512 threads / 8 waves; wave = 32x64 sub-tile. BK=64 single-buffer (R9 skeleton).
// Lean epilogue for tiles with no label overlap (~94%); full path otherwise.
__global__ __launch_bounds__(512) void simloss_kernel(
    const unsigned short* __restrict__ anchorT,
    const int* __restrict__ sortedLab,
    float* __restrict__ part,          // float2 [NT][BSZ]
    float* __restrict__ posAcc)        // [BSZ][4] {s1, w1, s2corr, cnt}
{
    __shared__ __align__(16) unsigned short As[8 * 512];   // 8 KB
    __shared__ __align__(16) unsigned short As2[8 * 512];
    __shared__ __align__(16) unsigned short Bs[8 * 512];
    __shared__ __align__(16) unsigned short Bs2[8 * 512];
    __shared__ float rowDT[2][BM][2];
    __shared__ float colDT[4][BN][2];
    __shared__ int rowLab[BM];
    __shared__ int colLab[BN];

    int It, Jt;
    decode_tile(blockIdx.x, It, Jt);
    const bool diag = (It == Jt);
    const int I0 = It * BM, J0 = Jt * BN;

    // label-range overlap (sorted): positives possible only if true
    const bool hasPos = (sortedLab[J0] <= sortedLab[I0 + BM - 1]);

    const int tid  = threadIdx.x;
    const int lane = tid & 63;
    const int w    = tid >> 6;       // 0..7
    const int rw   = w >> 1;         // row-group: rows rw*32..+31
    const int cw   = w & 1;          // col-group: cols cw*64..+63
    const int cl   = lane & 15;
    const int rg   = lane >> 4;
    const int laneOff = lane * 8;    // shorts (16 B)

    if (hasPos) {
        if (tid < BM) rowLab[tid] = sortedLab[I0 + tid];
        else if (tid < 2 * BM) colLab[tid - BM] = sortedLab[J0 + tid - BM];
    }

    f32x4 acc[2][4];
    #pragma unroll
    for (int f = 0; f < 2; f++)
        #pragma unroll
        for (int g = 0; g < 4; g++)
            acc[f][g] = (f32x4){0.f, 0.f, 0.f, 0.f};

    #pragma unroll
    for (int kc = 0; kc < 4; kc++) {
        {
            const int C0 = kc * 2;
            const size_t ga0 = ((size_t)C0 * 512 + It * 8) * 512;
            const size_t gb0 = ((size_t)C0 * 512 + Jt * 8) * 512;
            const size_t ga1 = ((size_t)(C0 + 1) * 512 + It * 8) * 512;
            const size_t gb1 = ((size_t)(C0 + 1) * 512 + Jt * 8) * 512;
            gload_lds16(anchorT + ga0 + tid * 8, &As[w * 512]);
            gload_lds16(anchorT + gb0 + tid * 8, &Bs[w * 512]);
            gload_lds16(anchorT + ga1 + tid * 8, &As2[w * 512]);
            gload_lds16(anchorT + gb1 + tid * 8, &Bs2[w * 512]);
        }
        __syncthreads();
        #pragma unroll
        for (int ks = 0; ks < 2; ks++) {
            const unsigned short* aB = (ks == 0 ? As : As2) + (rw * 2) * 512 + laneOff;
            const unsigned short* bB = (ks == 0 ? Bs : Bs2) + (cw * 4) * 512 + laneOff;
            const bf16x8 a0 = *(const bf16x8*)(aB);
            const bf16x8 a1 = *(const bf16x8*)(aB + 512);
            const bf16x8 b0 = *(const bf16x8*)(bB);
            const bf16x8 b1 = *(const bf16x8*)(bB + 512);
            const bf16x8 b2 = *(const bf16x8*)(bB + 1024);
            const bf16x8 b3 = *(const bf16x8*)(bB + 1536);
            acc[0][0] = __builtin_amdgcn_mfma_f32_16x16x32_bf16(a0, b0, acc[0][0], 0, 0, 0);
            acc[0][1] = __builtin_amdgcn_mfma_f32_16x16x32_bf16(a0, b1, acc[0][1], 0, 0, 0);
            acc[0][2] = __builtin_amdgcn_mfma_f32_16x16x32_bf16(a0, b2, acc[0][2], 0, 0, 0);
            acc[0][3] = __builtin_amdgcn_mfma_f32_16x16x32_bf16(a0, b3, acc[0][3], 0, 0, 0);
            acc[1][0] = __builtin_amdgcn_mfma_f32_16x16x32_bf16(a1, b0, acc[1][0], 0, 0, 0);
            acc[1][1] = __builtin_amdgcn_mfma_f32_16x16x32_bf16(a1, b1, acc[1][1], 0, 0, 0);
            acc[1][2] = __builtin_amdgcn_mfma_f32_16x16x32_bf16(a1, b2, acc[1][2], 0, 0, 0);
            acc[1][3] = __builtin_amdgcn_mfma_f32_16x16x32_bf16(a1, b3, acc[1][3], 0, 0, 0);
        }
        __syncthreads();
    }

    // ---- epilogue ----
    float rd[2][4], rt[2][4], cd[4], ct[4];
    #pragma unroll
    for (int f = 0; f < 2; f++)
        #pragma unroll
        for (int r = 0; r < 4; r++) { rd[f][r] = 0.f; rt[f][r] = 0.f; }
    #pragma unroll
    for (int g = 0; g < 4; g++) { cd[g] = 0.f; ct[g] = 0.f; }

    if (!hasPos) {
        // LEAN: off-diag guaranteed, no labels, no self, no branches
        #pragma unroll
        for (int f = 0; f < 2; f++) {
            #pragma unroll
            for (int g = 0; g < 4; g++) {
                const f32x4 c = acc[f][g];
                #pragma unroll
                for (int r = 0; r < 4; r++) {
                    const float s  = c[r];
                    const float e  = fast_exp2(fmaf(s, K_E1, K_E2));
                    const float wn = fmaxf(fmaf(s, K_N1, K_N2), 1.0f);
                    const float we = wn * e;
                    rd[f][r] += e;  rt[f][r] += we;
                    cd[g]    += e;  ct[g]    += we;
                }
            }
        }
    } else {
        int ljr[4], gjr[4];
        #pragma unroll
        for (int g = 0; g < 4; g++) {
            const int cidx = cw * 64 + g * 16 + cl;
            ljr[g] = colLab[cidx];
            gjr[g] = J0 + cidx;
        }
        #pragma unroll
        for (int f = 0; f < 2; f++) {
            int li[4], gi[4];
            #pragma unroll
            for (int r = 0; r < 4; r++) {
                const int ridx = rw * 32 + f * 16 + rg * 4 + r;
                li[r] = rowLab[ridx];
                gi[r] = I0 + ridx;
            }
            #pragma unroll
            for (int g = 0; g < 4; g++) {
                const int lj = ljr[g];
                const bool granule = (rw * 2 + f) == (cw * 4 + g);
                const f32x4 c = acc[f][g];
                #pragma unroll
                for (int r = 0; r < 4; r++) {
                    const float s = c[r];
                    const bool self = diag && granule && ((rg * 4 + r) == cl);
                    const float e  = self ? 0.f : fast_exp2(fmaf(s, K_E1, K_E2));
                    const float wn = fmaxf(fmaf(s, K_N1, K_N2), 1.0f);
                    const float we = wn * e;
                    rd[f][r] += e;  rt[f][r] += we;
                    if (!diag) { cd[g] += e; ct[g] += we; }
                    if (li[r] == lj && !self) {
                        const float wp = fmaxf(1.5f - s, 1.0f);
                        const float slp = fmaf(s, K_INVT, -K_INVT) * wp;
                        float* pi = posAcc + (size_t)gi[r] * 4;
                        atomicAdd(pi + 0, slp);
                        atomicAdd(pi + 1, wp);
                        atomicAdd(pi + 2, we);
                        atomicAdd(pi + 3, 1.0f);
                        if (!diag) {
                            float* pj = posAcc + (size_t)gjr[g] * 4;
                            atomicAdd(pj + 0, slp);
                            atomicAdd(pj + 1, wp);
                            atomicAdd(pj + 2, we);
                            atomicAdd(pj + 3, 1.0f);
                        }
                    }
                }
            }
        }
    }

    // ---- common reductions ----
    #pragma unroll
    for (int f = 0; f < 2; f++)
        #pragma unroll
        for (int r = 0; r < 4; r++) {
            #pragma unroll
            for (int off = 1; off < 16; off <<= 1) {
                rd[f][r] += __shfl_xor(rd[f][r], off, 64);
                rt[f][r] += __shfl_xor(rt[f][r], off, 64);
            }
        }
    if (cl == 0) {
        #pragma unroll
        for (int f = 0; f < 2; f++)
            #pragma unroll
            for (int r = 0; r < 4; r++) {
                const int row = rw * 32 + f * 16 + rg * 4 + r;
                rowDT[cw][row][0] = rd[f][r];
                rowDT[cw][row][1] = rt[f][r];
            }
    }
    if (!diag) {
        #pragma unroll
        for (int g = 0; g < 4; g++) {
            cd[g] += __shfl_xor(cd[g], 16, 64);
            cd[g] += __shfl_xor(cd[g], 32, 64);
            ct[g] += __shfl_xor(ct[g], 16, 64);
            ct[g] += __shfl_xor(ct[g], 32, 64);
        }
        if (rg == 0) {
            #pragma unroll
            for (int g = 0; g < 4; g++) {
                const int col = cw * 64 + g * 16 + cl;
                colDT[rw][col][0] = cd[g];
                colDT[rw][col][1] = ct[g];
            }
        }
    }

    __syncthreads();
    if (tid < BM) {
        float2 v;
        v.x = rowDT[0][tid][0] + rowDT[1][tid][0];
        v.y = rowDT[0][tid][1] + rowDT[1][tid][1];
        ((float2*)part)[(size_t)Jt * BSZ + I0 + tid] = v;
    } else if (tid < 2 * BM && !diag) {
        const int c = tid - BM;
        float2 v;
        v.x = colDT[0][c][0] + colDT[1][c][0] + colDT[2][c][0] + colDT[3][c][0];
        v.y = colDT[0][c][1] + colDT[1][c][1] + colDT[2][c][1] + colDT[3][c][1];
        ((float2*)part)[(size_t)It * BSZ + J0 + c] = v;
    }
}

// ---------------- wide per-row combine + grid-wide final (done-counter) ----------------
__global__ __launch_bounds__(256) void reduce_final_kernel(
    const float* __restrict__ part, const float* __restrict__ posAcc,
    double* __restrict__ partial, unsigned int* __restrict__ counter,
    float* __restrict__ out)
{
    const int t   = threadIdx.x;
    const int row = blockIdx.x * 32 + (t >> 3);
    const int sg  = t & 7;
    float dsum = 0.f, T2 = 0.f;
    const float2* p2 = (const float2*)part;
    #pragma unroll
    for (int j = 0; j < 8; j++) {
        const float2 v = p2[(size_t)(sg * 8 + j) * BSZ + row];
        dsum += v.x; T2 += v.y;
    }
    #pragma unroll
    for (int off = 1; off < 8; off <<= 1) {
        dsum += __shfl_xor(dsum, off, 64);
        T2   += __shfl_xor(T2,   off, 64);
    }
    __shared__ double sp[32], sn[32];
    if (sg == 0) {
        const float4 pa = ((const float4*)posAcc)[row];   // {s1, w1, s2corr, cnt}
        const float s1 = pa.x, w1 = pa.y, s2 = T2 - pa.z, cnt = pa.w;
        const float pc = fmaxf(cnt, 1.0f);
        const float nc = fmaxf(8191.0f - cnt, 1.0f);
        const float ld = logf(dsum);
        sp[t >> 3] = (double)((s1 - ld * w1) / pc);
        sn[t >> 3] = (double)((s2 / dsum) / nc);
    }
    __syncthreads();
    __shared__ bool amLast;
    if (t < 32) {
        double p = sp[t], n = sn[t];
        #pragma unroll
        for (int off = 1; off < 32; off <<= 1) {
            p += __shfl_xor(p, off, 64);
            n += __shfl_xor(n, off, 64);
        }
        if (t == 0) {
            partial[blockIdx.x * 2 + 0] = p;
            partial[blockIdx.x * 2 + 1] = n;
            __threadfence();
            amLast = (atomicAdd(counter, 1u) == 255u);
        }
    }
    __syncthreads();
    if (amLast) {
        __threadfence();
        __shared__ double fp[256], fn[256];
        volatile double* vp = (volatile double*)partial;
        fp[t] = vp[t * 2 + 0];
        fn[t] = vp[t * 2 + 1];
        __syncthreads();
        for (int s = 128; s > 0; s >>= 1) {
            if (t < s) { fp[t] += fp[t + s]; fn[t] += fn[t + s]; }
            __syncthreads();
        }
        if (t == 0) out[0] = (float)(-fp[0] / (double)BSZ + 0.3 * (fn[0] / (double)BSZ));
    }
}

extern "C" void kernel_launch(void* const* d_in, const int* in_sizes, int n_in,
                              void* d_out, int out_size, void* d_ws, size_t ws_size,
                              hipStream_t stream) {
    const float* feat = (const float*)d_in[0];
    const int* labels = (const int*)d_in[1];
    float* out = (float*)d_out;

    char* ws = (char*)d_ws;
    unsigned short* anchorT = (unsigned short*)ws;                       // 4 MB MFMA-native (sorted)
    const size_t anchorBytes = (size_t)BSZ * DDIM * sizeof(unsigned short);
    float* part = (float*)(ws + anchorBytes);                            // 64*8192 float2 = 4 MB
    const size_t partBytes = (size_t)NT * BSZ * 2 * sizeof(float);
    float* posAcc = (float*)(ws + anchorBytes + partBytes);              // 128 KB
    const size_t posBytes = (size_t)BSZ * 4 * sizeof(float);
    char* p = ws + anchorBytes + partBytes + posBytes;
    int* s2o       = (int*)p;            p += BSZ * sizeof(int);         // 32 KB
    int* sortedLab = (int*)p;            p += BSZ * sizeof(int);         // 32 KB
    double* partial = (double*)p;        p += 256 * 2 * sizeof(double);  // 4 KB
    unsigned int* counter = (unsigned int*)p;

    sort_kernel<<<1, 256, 0, stream>>>(labels, s2o, sortedLab, counter);
    norm_kernel<<<BSZ / 16, 256, 0, stream>>>(feat, s2o, anchorT, posAcc);
    simloss_kernel<<<NTRI, 512, 0, stream>>>(anchorT, sortedLab, part, posAcc);
    reduce_final_kernel<<<BSZ / 32, 256, 0, stream>>>(part, posAcc, partial, counter, out);
}

// Round 12
// 116.970 us; speedup vs baseline: 1.3351x; 1.3351x over previous
//
#include <hip/hip_runtime.h>

#define BSZ  8192
#define DDIM 256
#define BM 128
#define BN 128
#define NT   64                  // tiles per dimension
#define NTRI (NT * (NT + 1) / 2) // 2080 upper-triangle tiles

typedef float f32x4 __attribute__((ext_vector_type(4)));
typedef short bf16x8 __attribute__((ext_vector_type(8)));

__device__ __forceinline__ unsigned short f32_to_bf16(float f) {
    unsigned int u = __float_as_uint(f);
    u += 0x7fffu + ((u >> 16) & 1u);   // RNE
    return (unsigned short)(u >> 16);
}

// schedulable native exp2 (NOT asm volatile -- R11 showed that serializes)
#if __has_builtin(__builtin_amdgcn_exp2f)
__device__ __forceinline__ float fast_exp2(float x) { return __builtin_amdgcn_exp2f(x); }
#else
__device__ __forceinline__ float fast_exp2(float x) {
    float r;
    asm("v_exp_f32 %0, %1" : "=v"(r) : "v"(x));
    return r;
}
#endif

// epilogue constants
#define K_E1   20.60992915555662f    // (1/T)*log2(e)
#define K_E2  -20.60992915555662f
#define K_INVT 14.285714285714286f   // 1/T
#define K_N1   1.4285714285714286f   // 1/(1-0.3)
#define K_N2   0.5714285714285714f   // 0.4/0.7

// ---------------- triangular tile decode (supertile-swizzled) ----------------
__device__ __forceinline__ void decode_tile(int t, int& It, int& Jt) {
    const int off1 = 136, off2 = 392, off3 = 648, off4 = 904, off5 = 1040,
              off6 = 1296, off7 = 1552, off8 = 1688, off9 = 1944;
    int b = (t >= off1) + (t >= off2) + (t >= off3) + (t >= off4) + (t >= off5)
          + (t >= off6) + (t >= off7) + (t >= off8) + (t >= off9);
    int si, sj, r0;
    switch (b) {
        case 0: si = 0; sj = 0; r0 = 0;    break;
        case 1: si = 0; sj = 1; r0 = off1; break;
        case 2: si = 0; sj = 2; r0 = off2; break;
        case 3: si = 0; sj = 3; r0 = off3; break;
        case 4: si = 1; sj = 1; r0 = off4; break;
        case 5: si = 1; sj = 2; r0 = off5; break;
        case 6: si = 1; sj = 3; r0 = off6; break;
        case 7: si = 2; sj = 2; r0 = off7; break;
        case 8: si = 2; sj = 3; r0 = off8; break;
        default: si = 3; sj = 3; r0 = off9; break;
    }
    const int rr = t - r0;
    int il, jl;
    if (si == sj) {
        il = 0;
        #pragma unroll
        for (int q = 1; q < 16; q++) if (rr >= (16 * q - (q * (q - 1)) / 2)) il = q;
        jl = il + (rr - (16 * il - (il * (il - 1)) / 2));
    } else {
        il = rr >> 4;
        jl = rr & 15;
    }
    It = si * 16 + il;
    Jt = sj * 16 + jl;
}

// ---------------- L2-normalize rows; coalesced MFMA-native output; zero posAcc+counter ----------------
// 512 blocks, one 16-row tile R = blockIdx.x each.
// anchorT tile T = C*512 + R, 1 KB each; lane l16 = (row%16)+16*((k%32)/8) holds 8 shorts.
__global__ __launch_bounds__(256) void norm_kernel(const float* __restrict__ feat,
                                                   unsigned short* __restrict__ anchorT,
                                                   float* __restrict__ posAcc,
                                                   unsigned int* __restrict__ counter) {
    __shared__ __align__(16) unsigned short img[8 * 512];    // 8 KB: 8 x 1KB tiles
    const int tid  = threadIdx.x;
    const int wid  = tid >> 6;
    const int lane = tid & 63;
    const int R    = blockIdx.x;          // 16-row tile
    const int R0   = R * 16;

    if (tid < 64) posAcc[blockIdx.x * 64 + tid] = 0.0f;       // 512*64 = 32768 = BSZ*4
    if (blockIdx.x == 0 && tid == 0) *counter = 0u;

    #pragma unroll
    for (int it = 0; it < 4; it++) {
        const int row = R0 + it * 4 + wid;
        const float4 v = ((const float4*)(feat + (size_t)row * DDIM))[lane];
        float ss = v.x * v.x + v.y * v.y + v.z * v.z + v.w * v.w;
        #pragma unroll
        for (int off = 32; off > 0; off >>= 1) ss += __shfl_xor(ss, off, 64);
        const float inv = rsqrtf(ss);
        ushort4 o;
        o.x = f32_to_bf16(v.x * inv);
        o.y = f32_to_bf16(v.y * inv);
        o.z = f32_to_bf16(v.z * inv);
        o.w = f32_to_bf16(v.w * inv);
        const int C    = lane >> 3;                           // k/32 (k = lane*4)
        const int l16  = (row & 15) + (((lane >> 1) & 3) << 4);
        *(ushort4*)(&img[C * 512 + l16 * 8 + (lane & 1) * 4]) = o;
    }
    __syncthreads();
    #pragma unroll
    for (int p = 0; p < 2; p++) {
        const int c = p * 4 + wid;                            // chunk 0..7 (= C)
        *(bf16x8*)(anchorT + ((size_t)(c * 512 + R)) * 512 + lane * 8) =
            *(const bf16x8*)(&img[c * 512 + lane * 8]);
    }
}

// ---------------- async global -> LDS, 16B/lane ----------------
__device__ __forceinline__ void gload_lds16(const unsigned short* g, unsigned short* l) {
    __builtin_amdgcn_global_load_lds(
        (const __attribute__((address_space(1))) void*)g,
        (__attribute__((address_space(3))) void*)l, 16, 0, 0);
}

// ---------------- fused sim-tile + loss partials (upper triangle) ----------------
// 512 threads / 8 waves; wave = 32x64 sub-tile (2 A-frag x 4 B-frag, 32 AGPR acc).
// BK=64, single-buffer (proven R9 skeleton, 54.4 us).
// part: float2 {dsum,T2} plane [NT][BSZ]; rare positives -> global atomics posAcc.
__global__ __launch_bounds__(512) void simloss_kernel(
    const unsigned short* __restrict__ anchorT,
    const int* __restrict__ labels,
    float* __restrict__ part,          // float2 [NT][BSZ]
    float* __restrict__ posAcc)        // [BSZ][4] {s1, w1, s2corr, cnt}
{
    __shared__ __align__(16) unsigned short As[8 * 512];   // 8 KB
    __shared__ __align__(16) unsigned short As2[8 * 512];
    __shared__ __align__(16) unsigned short Bs[8 * 512];
    __shared__ __align__(16) unsigned short Bs2[8 * 512];
    __shared__ float rowDT[2][BM][2];
    __shared__ float colDT[4][BN][2];
    __shared__ int rowLab[BM];
    __shared__ int colLab[BN];

    int It, Jt;
    decode_tile(blockIdx.x, It, Jt);
    const bool diag = (It == Jt);
    const int I0 = It * BM, J0 = Jt * BN;

    const int tid  = threadIdx.x;
    const int lane = tid & 63;
    const int w    = tid >> 6;       // 0..7
    const int rw   = w >> 1;         // row-group: rows rw*32..+31
    const int cw   = w & 1;          // col-group: cols cw*64..+63
    const int cl   = lane & 15;
    const int rg   = lane >> 4;
    const int laneOff = lane * 8;    // shorts (16 B)

    if (tid < BM) rowLab[tid] = labels[I0 + tid];
    else if (tid < 2 * BM) colLab[tid - BM] = labels[J0 + tid - BM];

    f32x4 acc[2][4];
    #pragma unroll
    for (int f = 0; f < 2; f++)
        #pragma unroll
        for (int g = 0; g < 4; g++)
            acc[f][g] = (f32x4){0.f, 0.f, 0.f, 0.f};

    #pragma unroll
    for (int kc = 0; kc < 4; kc++) {
        {
            const int C0 = kc * 2;
            const size_t ga0 = ((size_t)C0 * 512 + It * 8) * 512;
            const size_t gb0 = ((size_t)C0 * 512 + Jt * 8) * 512;
            const size_t ga1 = ((size_t)(C0 + 1) * 512 + It * 8) * 512;
            const size_t gb1 = ((size_t)(C0 + 1) * 512 + Jt * 8) * 512;
            gload_lds16(anchorT + ga0 + tid * 8, &As[w * 512]);
            gload_lds16(anchorT + gb0 + tid * 8, &Bs[w * 512]);
            gload_lds16(anchorT + ga1 + tid * 8, &As2[w * 512]);
            gload_lds16(anchorT + gb1 + tid * 8, &Bs2[w * 512]);
        }
        __syncthreads();
        #pragma unroll
        for (int ks = 0; ks < 2; ks++) {
            const unsigned short* aB = (ks == 0 ? As : As2) + (rw * 2) * 512 + laneOff;
            const unsigned short* bB = (ks == 0 ? Bs : Bs2) + (cw * 4) * 512 + laneOff;
            const bf16x8 a0 = *(const bf16x8*)(aB);
            const bf16x8 a1 = *(const bf16x8*)(aB + 512);
            const bf16x8 b0 = *(const bf16x8*)(bB);
            const bf16x8 b1 = *(const bf16x8*)(bB + 512);
            const bf16x8 b2 = *(const bf16x8*)(bB + 1024);
            const bf16x8 b3 = *(const bf16x8*)(bB + 1536);
            acc[0][0] = __builtin_amdgcn_mfma_f32_16x16x32_bf16(a0, b0, acc[0][0], 0, 0, 0);
            acc[0][1] = __builtin_amdgcn_mfma_f32_16x16x32_bf16(a0, b1, acc[0][1], 0, 0, 0);
            acc[0][2] = __builtin_amdgcn_mfma_f32_16x16x32_bf16(a0, b2, acc[0][2], 0, 0, 0);
            acc[0][3] = __builtin_amdgcn_mfma_f32_16x16x32_bf16(a0, b3, acc[0][3], 0, 0, 0);
            acc[1][0] = __builtin_amdgcn_mfma_f32_16x16x32_bf16(a1, b0, acc[1][0], 0, 0, 0);
            acc[1][1] = __builtin_amdgcn_mfma_f32_16x16x32_bf16(a1, b1, acc[1][1], 0, 0, 0);
            acc[1][2] = __builtin_amdgcn_mfma_f32_16x16x32_bf16(a1, b2, acc[1][2], 0, 0, 0);
            acc[1][3] = __builtin_amdgcn_mfma_f32_16x16x32_bf16(a1, b3, acc[1][3], 0, 0, 0);
        }
        __syncthreads();
    }

    // ---- epilogue: hot path dsum/T2; rare positives -> atomics ----
    int ljr[4], gjr[4];
    #pragma unroll
    for (int g = 0; g < 4; g++) {
        const int cidx = cw * 64 + g * 16 + cl;
        ljr[g] = colLab[cidx];
        gjr[g] = J0 + cidx;
    }
    float cd[4] = {0.f, 0.f, 0.f, 0.f}, ct[4] = {0.f, 0.f, 0.f, 0.f};

    #pragma unroll
    for (int f = 0; f < 2; f++) {
        float rd[4] = {0.f, 0.f, 0.f, 0.f}, rt[4] = {0.f, 0.f, 0.f, 0.f};
        int li[4], gi[4];
        #pragma unroll
        for (int r = 0; r < 4; r++) {
            const int ridx = rw * 32 + f * 16 + rg * 4 + r;
            li[r] = rowLab[ridx];
            gi[r] = I0 + ridx;
        }
        #pragma unroll
        for (int g = 0; g < 4; g++) {
            const int lj = ljr[g];
            const bool granule = (rw * 2 + f) == (cw * 4 + g);   // 16x16 block on tile diagonal
            const f32x4 c = acc[f][g];
            #pragma unroll
            for (int r = 0; r < 4; r++) {
                const float s = c[r];
                const bool self = diag && granule && ((rg * 4 + r) == cl);
                const float e  = self ? 0.f : fast_exp2(fmaf(s, K_E1, K_E2));
                const float wn = fmaxf(fmaf(s, K_N1, K_N2), 1.0f);
                const float we = wn * e;
                rd[r] += e;  rt[r] += we;
                if (!diag) { cd[g] += e; ct[g] += we; }
                if (li[r] == lj && !self) {   // rare (~0.1%)
                    const float wp = fmaxf(1.5f - s, 1.0f);
                    const float slp = fmaf(s, K_INVT, -K_INVT) * wp;
                    float* pi = posAcc + (size_t)gi[r] * 4;
                    atomicAdd(pi + 0, slp);
                    atomicAdd(pi + 1, wp);
                    atomicAdd(pi + 2, we);
                    atomicAdd(pi + 3, 1.0f);
                    if (!diag) {
                        float* pj = posAcc + (size_t)gjr[g] * 4;
                        atomicAdd(pj + 0, slp);
                        atomicAdd(pj + 1, wp);
                        atomicAdd(pj + 2, we);
                        atomicAdd(pj + 3, 1.0f);
                    }
                }
            }
        }
        #pragma unroll
        for (int r = 0; r < 4; r++) {
            #pragma unroll
            for (int off = 1; off < 16; off <<= 1) {
                rd[r] += __shfl_xor(rd[r], off, 64);
                rt[r] += __shfl_xor(rt[r], off, 64);
            }
        }
        if (cl == 0) {
            #pragma unroll
            for (int r = 0; r < 4; r++) {
                const int row = rw * 32 + f * 16 + rg * 4 + r;
                rowDT[cw][row][0] = rd[r];
                rowDT[cw][row][1] = rt[r];
            }
        }
    }
    if (!diag) {
        #pragma unroll
        for (int g = 0; g < 4; g++) {
            cd[g] += __shfl_xor(cd[g], 16, 64);
            cd[g] += __shfl_xor(cd[g], 32, 64);
            ct[g] += __shfl_xor(ct[g], 16, 64);
            ct[g] += __shfl_xor(ct[g], 32, 64);
        }
        if (rg == 0) {
            #pragma unroll
            for (int g = 0; g < 4; g++) {
                const int col = cw * 64 + g * 16 + cl;
                colDT[rw][col][0] = cd[g];
                colDT[rw][col][1] = ct[g];
            }
        }
    }

    __syncthreads();
    if (tid < BM) {
        float2 v;
        v.x = rowDT[0][tid][0] + rowDT[1][tid][0];
        v.y = rowDT[0][tid][1] + rowDT[1][tid][1];
        ((float2*)part)[(size_t)Jt * BSZ + I0 + tid] = v;
    } else if (tid < 2 * BM && !diag) {
        const int c = tid - BM;
        float2 v;
        v.x = colDT[0][c][0] + colDT[1][c][0] + colDT[2][c][0] + colDT[3][c][0];
        v.y = colDT[0][c][1] + colDT[1][c][1] + colDT[2][c][1] + colDT[3][c][1];
        ((float2*)part)[(size_t)It * BSZ + J0 + c] = v;
    }
}

// ---------------- wide per-row combine + grid-wide final (done-counter) ----------------
// 256 blocks; 8 threads per row, 8 slabs each; counter target 255.
__global__ __launch_bounds__(256) void reduce_final_kernel(
    const float* __restrict__ part, const float* __restrict__ posAcc,
    double* __restrict__ partial, unsigned int* __restrict__ counter,
    float* __restrict__ out)
{
    const int t   = threadIdx.x;
    const int row = blockIdx.x * 32 + (t >> 3);
    const int sg  = t & 7;
    float dsum = 0.f, T2 = 0.f;
    const float2* p2 = (const float2*)part;
    #pragma unroll
    for (int j = 0; j < 8; j++) {
        const float2 v = p2[(size_t)(sg * 8 + j) * BSZ + row];
        dsum += v.x; T2 += v.y;
    }
    #pragma unroll
    for (int off = 1; off < 8; off <<= 1) {
        dsum += __shfl_xor(dsum, off, 64);
        T2   += __shfl_xor(T2,   off, 64);
    }
    __shared__ double sp[32], sn[32];
    if (sg == 0) {
        const float4 pa = ((const float4*)posAcc)[row];   // {s1, w1, s2corr, cnt}
        const float s1 = pa.x, w1 = pa.y, s2 = T2 - pa.z, cnt = pa.w;
        const float pc = fmaxf(cnt, 1.0f);
        const float nc = fmaxf(8191.0f - cnt, 1.0f);
        const float ld = logf(dsum);
        sp[t >> 3] = (double)((s1 - ld * w1) / pc);
        sn[t >> 3] = (double)((s2 / dsum) / nc);
    }
    __syncthreads();
    __shared__ bool amLast;
    if (t < 32) {
        double p = sp[t], n = sn[t];
        #pragma unroll
        for (int off = 1; off < 32; off <<= 1) {
            p += __shfl_xor(p, off, 64);
            n += __shfl_xor(n, off, 64);
        }
        if (t == 0) {
            partial[blockIdx.x * 2 + 0] = p;
            partial[blockIdx.x * 2 + 1] = n;
            __threadfence();
            amLast = (atomicAdd(counter, 1u) == 255u);
        }
    }
    __syncthreads();
    if (amLast) {
        __threadfence();
        __shared__ double fp[256], fn[256];
        volatile double* vp = (volatile double*)partial;
        fp[t] = vp[t * 2 + 0];
        fn[t] = vp[t * 2 + 1];
        __syncthreads();
        for (int s = 128; s > 0; s >>= 1) {
            if (t < s) { fp[t] += fp[t + s]; fn[t] += fn[t + s]; }
            __syncthreads();
        }
        if (t == 0) out[0] = (float)(-fp[0] / (double)BSZ + 0.3 * (fn[0] / (double)BSZ));
    }
}

extern "C" void kernel_launch(void* const* d_in, const int* in_sizes, int n_in,
                              void* d_out, int out_size, void* d_ws, size_t ws_size,
                              hipStream_t stream) {
    const float* feat = (const float*)d_in[0];
    const int* labels = (const int*)d_in[1];
    float* out = (float*)d_out;

    char* ws = (char*)d_ws;
    unsigned short* anchorT = (unsigned short*)ws;                       // 4 MB MFMA-native
    const size_t anchorBytes = (size_t)BSZ * DDIM * sizeof(unsigned short);
    float* part = (float*)(ws + anchorBytes);                            // 64*8192 float2 = 4 MB
    const size_t partBytes = (size_t)NT * BSZ * 2 * sizeof(float);
    float* posAcc = (float*)(ws + anchorBytes + partBytes);              // 128 KB
    const size_t posBytes = (size_t)BSZ * 4 * sizeof(float);
    double* partial = (double*)(ws + anchorBytes + partBytes + posBytes); // 4 KB
    unsigned int* counter = (unsigned int*)(ws + anchorBytes + partBytes + posBytes + 4096);

    norm_kernel<<<BSZ / 16, 256, 0, stream>>>(feat, anchorT, posAcc, counter);
    simloss_kernel<<<NTRI, 512, 0, stream>>>(anchorT, labels, part, posAcc);
    reduce_final_kernel<<<BSZ / 32, 256, 0, stream>>>(part, posAcc, partial, counter, out);
}